// Round 4
// baseline (2362.718 us; speedup 1.0000x reference)
//
#include <hip/hip_runtime.h>
#include <stdint.h>

// ---------------------------------------------------------------------------
// GRU encoder (B=128,T=512,D=512,H=512,L=256), MI355X gfx950.
//
// R8 = R7 (proven flag protocol, 32 blocks x 512 thr, LDS-staged h) with the
// store path fixed:
//   - h stores were 2048 scattered 2B write-through device-scope stores per
//     block per step (1024B stride), serialized behind vmcnt(0). Now: gates
//     write a 16x128 LDS tile (ts), barrier, then 512 coalesced 8B
//     global_store_dwordx2 sc0 sc1 (256B runs per row) + per-thread drain.
//   - fill: block's OWN 128-col slice copied LDS->LDS from ts (no global
//     round trip); only the 3 peer slices are loaded coherently. Pollers
//     poll only the 3 peer flags (own-flag L3 propagation off the chain).
// Induction unchanged: flag[b]=t+1 => b stored h_{t+1} (drained, coalesced)
// AND finished its fill-reads of h_t. Writer overwrites h_t's slot only at
// end of step t+1 after seeing peer flags >= t+1.
// ---------------------------------------------------------------------------

typedef short short8 __attribute__((ext_vector_type(8)));
typedef float f32x4 __attribute__((ext_vector_type(4)));
typedef int int4v __attribute__((ext_vector_type(4)));

#define NB 128
#define NT 512
#define ND 512
#define NH 512
#define NG 1536   // 3H
#define HSLOT (NB * NH)  // shorts per h slot (128 KB)

__device__ __forceinline__ unsigned short f2bf(float f) {
  union { float f; unsigned u; } v; v.f = f;
  unsigned r = v.u + 0x7fffu + ((v.u >> 16) & 1u);  // RNE
  return (unsigned short)(r >> 16);
}
__device__ __forceinline__ float bf2f(unsigned short u) {
  union { unsigned u; float f; } v; v.u = ((unsigned)u) << 16; return v.f;
}
__device__ __forceinline__ float sigmoid_f(float x) {
  float e = __builtin_amdgcn_exp2f(-1.4426950408889634f * x);
  return __builtin_amdgcn_rcpf(1.0f + e);
}
__device__ __forceinline__ float tanh_f(float x) {
  float e = __builtin_amdgcn_exp2f(2.8853900817779268f * x);
  return 1.0f - 2.0f * __builtin_amdgcn_rcpf(1.0f + e);
}
__device__ __forceinline__ short8 pack8(float4 a, float4 b) {
  short8 s;
  s[0] = (short)f2bf(a.x); s[1] = (short)f2bf(a.y);
  s[2] = (short)f2bf(a.z); s[3] = (short)f2bf(a.w);
  s[4] = (short)f2bf(b.x); s[5] = (short)f2bf(b.y);
  s[6] = (short)f2bf(b.z); s[7] = (short)f2bf(b.w);
  return s;
}

// two coherent 16B loads + one drain (LDS fill path, peer slices)
__device__ __forceinline__ void load16x2_s(const unsigned short* p0,
                                           const unsigned short* p1,
                                           int4v* v0, int4v* v1) {
  asm volatile(
      "global_load_dwordx4 %0, %2, off sc0 sc1\n\t"
      "global_load_dwordx4 %1, %3, off sc0 sc1\n\t"
      "s_waitcnt vmcnt(0)"
      : "=&v"(*v0), "=&v"(*v1) : "v"(p0), "v"(p1) : "memory");
}

// one coalesced coherent 8B store + drain (h store path)
__device__ __forceinline__ void store8_s(unsigned short* p, unsigned long long v) {
  asm volatile(
      "global_store_dwordx2 %0, %1, off sc0 sc1\n\t"
      "s_waitcnt vmcnt(0)"
      :: "v"(p), "v"(v) : "memory");
}

__device__ __forceinline__ unsigned poll_s(const unsigned* p) {
  unsigned f;
  asm volatile("global_load_dword %0, %1, off sc0 sc1\n\t"
               "s_waitcnt vmcnt(0)" : "=v"(f) : "v"(p) : "memory");
  return f;
}

__device__ __forceinline__ void fstore_s(unsigned* p, unsigned v) {
  asm volatile("global_store_dword %0, %1, off sc0 sc1"
               :: "v"(p), "v"(v) : "memory");
}

// ---------------------------------------------------------------------------
// IG = x @ Wih^T + bias, bf16 out. M=65536, N=1536, K=512.
// Grid dim3(12,512): bn fastest so the 12 blocks sharing one x-panel co-run.
// ---------------------------------------------------------------------------
__global__ __launch_bounds__(256) void ig_gemm(
    const float* __restrict__ x, const float* __restrict__ Wih,
    const float* __restrict__ bias, unsigned short* __restrict__ IG) {
  __shared__ unsigned short As[128 * 40];
  __shared__ unsigned short Bs[128 * 40];
  const int tid = threadIdx.x;
  const int bn = blockIdx.x, bm = blockIdx.y;
  const int lane = tid & 63, w = tid >> 6;
  const int wm = w >> 1, wn = w & 1;
  const int l15 = lane & 15, q = lane >> 4;

  f32x4 acc[4][4] = {};

  for (int kt = 0; kt < 16; ++kt) {
    __syncthreads();
#pragma unroll
    for (int j = 0; j < 4; ++j) {
      int fi = tid + 256 * j;
      int row = fi >> 3, kq = fi & 7;
      float4 v = *(const float4*)(x + (size_t)(bm * 128 + row) * ND + kt * 32 + kq * 4);
      ushort4 s = {f2bf(v.x), f2bf(v.y), f2bf(v.z), f2bf(v.w)};
      *(ushort4*)&As[row * 40 + kq * 4] = s;
    }
#pragma unroll
    for (int j = 0; j < 4; ++j) {
      int fi = tid + 256 * j;
      int row = fi >> 3, kq = fi & 7;
      float4 v = *(const float4*)(Wih + (size_t)(bn * 128 + row) * ND + kt * 32 + kq * 4);
      ushort4 s = {f2bf(v.x), f2bf(v.y), f2bf(v.z), f2bf(v.w)};
      *(ushort4*)&Bs[row * 40 + kq * 4] = s;
    }
    __syncthreads();

    short8 af[4], bf[4];
#pragma unroll
    for (int tm = 0; tm < 4; ++tm)
      af[tm] = *(const short8*)&As[(wm * 64 + tm * 16 + l15) * 40 + q * 8];
#pragma unroll
    for (int tn = 0; tn < 4; ++tn)
      bf[tn] = *(const short8*)&Bs[(wn * 64 + tn * 16 + l15) * 40 + q * 8];
#pragma unroll
    for (int tm = 0; tm < 4; ++tm)
#pragma unroll
      for (int tn = 0; tn < 4; ++tn)
        acc[tm][tn] = __builtin_amdgcn_mfma_f32_16x16x32_bf16(af[tm], bf[tn], acc[tm][tn], 0, 0, 0);
  }

#pragma unroll
  for (int tm = 0; tm < 4; ++tm) {
#pragma unroll
    for (int tn = 0; tn < 4; ++tn) {
      int col = bn * 128 + wn * 64 + tn * 16 + l15;
      float bb = bias[col];
#pragma unroll
      for (int i = 0; i < 4; ++i) {
        int row = bm * 128 + wm * 64 + tm * 16 + q * 4 + i;
        IG[(size_t)row * NG + col] = f2bf(acc[tm][tn][i] + bb);
      }
    }
  }
}

// ---------------------------------------------------------------------------
// Persistent GRU recurrence. 32 blocks x 512 threads.
// block: g = bid&7 (rows g*16..+16), cblk = bid>>3 (cols cblk*128..+128).
// wave w (0..7): 16 rows x 16 cols at col cblk*128 + w*16.
// flags[g*4 + cblk] = step count completed by that block.
// ---------------------------------------------------------------------------
template <bool USE_IG>
__global__ __launch_bounds__(512, 2) void gru_rec(
    const float* __restrict__ x, const float* __restrict__ Wih,
    const float* __restrict__ Whh, const float* __restrict__ bias,
    const float* __restrict__ bn, const unsigned short* __restrict__ IG,
    unsigned short* __restrict__ hbuf, unsigned* __restrict__ flags,
    float* __restrict__ hfin) {
  __shared__ unsigned short hs[16 * 512];  // h_t slab, swizzled (16 KB)
  __shared__ unsigned short ts[16 * 128];  // own h_{t+1} slice, row-major (4 KB)

  const int tid = threadIdx.x;
  const int lane = tid & 63;
  const int w = tid >> 6;                  // 0..7
  const int l15 = lane & 15, q = lane >> 4;
  const int bid = blockIdx.x;
  const int g = bid & 7, cblk = bid >> 3;
  const int col = cblk * 128 + w * 16 + l15;  // this lane's h column
  const int erow = g * 16 + q * 4;            // C-layout batch row base
  const int mrow = g * 16 + l15;              // A-fragment batch row (!USE_IG path)

  unsigned* const myflag = flags + g * 4 + cblk;
  const unsigned* const pollbase = flags + g * 4;  // 4 community flags

  // Whh B-fragments -> registers: 3 gates x 16 k-chunks (192 VGPRs)
  short8 bfr[3][16];
#pragma unroll
  for (int gt = 0; gt < 3; ++gt) {
    const float* src = Whh + (size_t)(gt * NH + col) * NH + q * 8;
#pragma unroll
    for (int kk = 0; kk < 16; ++kk) {
      float4 v0 = *(const float4*)(src + kk * 32);
      float4 v1 = *(const float4*)(src + kk * 32 + 4);
      bfr[gt][kk] = pack8(v0, v1);
    }
  }

  float bi_r = 0.f, bi_z = 0.f, bi_n = 0.f;
  if (!USE_IG) {
    bi_r = bias[col];
    bi_z = bias[NH + col];
    bi_n = bias[2 * NH + col];
  }
  const float bnv = bn[col];

  float hreg[4] = {0.f, 0.f, 0.f, 0.f};

  // fill indices (fixed per thread): 64 16B-slots per row, 2 per thread.
  const int frow = tid >> 5;          // 0..15
  const int fsi = (tid & 31) * 2;     // even slot index 0..62
  const int fr7 = frow & 7;
  const bool own_slot = ((fsi >> 4) == cblk);  // swizzle keeps 16-window

  // coalesced-store indices: 8B per thread
  const int srow = tid >> 5;          // 0..15
  const int scol = (tid & 31) * 4;    // shorts

  for (int t = 0; t < NT; ++t) {
    const unsigned short* hcur = hbuf + (size_t)(t & 1) * HSLOT;
    unsigned short* hnxt = hbuf + (size_t)((t & 1) ^ 1) * HSLOT;

    // IG loads first (plain cached loads; latency overlaps poll + fill).
    float igr[4], igz[4], ign[4];
    if (USE_IG) {
#pragma unroll
      for (int i = 0; i < 4; ++i) {
        const size_t base = ((size_t)(erow + i) * NT + t) * NG + col;
        igr[i] = bf2f(IG[base]);
        igz[i] = bf2f(IG[base + NH]);
        ign[i] = bf2f(IG[base + 2 * NH]);
      }
    }

    // wait for the 3 PEER blocks to have written h_t (own slice comes via ts)
    if (t > 0) {
      if (tid < 4 && tid != cblk) {
        const unsigned* fp = pollbase + tid;
        unsigned f = poll_s(fp);
        while ((int)f < t) f = poll_s(fp);
      }
      __syncthreads();
    }

    // cooperative fill: h_t[16x512] -> LDS, swizzled (LDS slot s holds
    // global slot s^(row&7)). Own 128-col slice comes from ts (LDS->LDS).
    if (t > 0 && own_slot) {
      const int ls0 = (fsi ^ fr7) & 15;
      const int ls1 = ((fsi + 1) ^ fr7) & 15;
      *(int4v*)&hs[frow * 512 + (fsi << 3)] =
          *(const int4v*)&ts[frow * 128 + ls0 * 8];
      *(int4v*)&hs[frow * 512 + ((fsi + 1) << 3)] =
          *(const int4v*)&ts[frow * 128 + ls1 * 8];
    } else {
      const unsigned short* hrow = hcur + (size_t)(g * 16 + frow) * NH;
      int4v v0, v1;
      load16x2_s(hrow + ((fsi ^ fr7) << 3), hrow + (((fsi + 1) ^ fr7) << 3),
                 &v0, &v1);
      *(int4v*)&hs[frow * 512 + (fsi << 3)] = v0;
      *(int4v*)&hs[frow * 512 + ((fsi + 1) << 3)] = v1;
    }
    __syncthreads();

    f32x4 ar = {0.f, 0.f, 0.f, 0.f};
    f32x4 az = {0.f, 0.f, 0.f, 0.f};
    f32x4 an = {0.f, 0.f, 0.f, 0.f};
    f32x4 ai = {0.f, 0.f, 0.f, 0.f};
    const int abase = l15 * 512;
    const int ar7 = (l15 & 7) << 3;
#pragma unroll
    for (int kk = 0; kk < 16; ++kk) {
      short8 afk = *(const short8*)&hs[abase + ((kk * 32 + q * 8) ^ ar7)];
      ar = __builtin_amdgcn_mfma_f32_16x16x32_bf16(afk, bfr[0][kk], ar, 0, 0, 0);
      az = __builtin_amdgcn_mfma_f32_16x16x32_bf16(afk, bfr[1][kk], az, 0, 0, 0);
      an = __builtin_amdgcn_mfma_f32_16x16x32_bf16(afk, bfr[2][kk], an, 0, 0, 0);
      if (!USE_IG) {
        const float* xp = x + ((size_t)mrow * NT + t) * ND + kk * 32 + q * 8;
        short8 xa = pack8(*(const float4*)xp, *(const float4*)(xp + 4));
#pragma unroll
        for (int gt = 0; gt < 3; ++gt) {
          const float* wp = Wih + (size_t)(gt * NH + col) * ND + kk * 32 + q * 8;
          short8 wf = pack8(*(const float4*)wp, *(const float4*)(wp + 4));
          if (gt == 0) ar = __builtin_amdgcn_mfma_f32_16x16x32_bf16(xa, wf, ar, 0, 0, 0);
          if (gt == 1) az = __builtin_amdgcn_mfma_f32_16x16x32_bf16(xa, wf, az, 0, 0, 0);
          if (gt == 2) ai = __builtin_amdgcn_mfma_f32_16x16x32_bf16(xa, wf, ai, 0, 0, 0);
        }
      }
    }

    // gates + h update
    unsigned short sv[4];
#pragma unroll
    for (int i = 0; i < 4; ++i) {
      float xr = USE_IG ? (ar[i] + igr[i]) : (ar[i] + bi_r);
      float xz = USE_IG ? (az[i] + igz[i]) : (az[i] + bi_z);
      float xin = USE_IG ? ign[i] : (ai[i] + bi_n);
      float r = sigmoid_f(xr);
      float z = sigmoid_f(xz);
      float n = tanh_f(xin + r * (an[i] + bnv));
      float hn2 = (1.f - z) * n + z * hreg[i];
      hreg[i] = hn2;
      sv[i] = f2bf(hn2);
      if (t == NT - 1) hfin[(size_t)(erow + i) * NH + col] = hn2;
    }

    if (t != NT - 1) {
      // transpose C-layout -> row-major 16x128 tile in LDS
#pragma unroll
      for (int i = 0; i < 4; ++i)
        ts[(q * 4 + i) * 128 + w * 16 + l15] = sv[i];
      __syncthreads();
      // coalesced coherent store: 8B per thread, 256B runs per row
      unsigned long long v8 = *(const unsigned long long*)&ts[srow * 128 + scol];
      store8_s(hnxt + (size_t)(g * 16 + srow) * NH + cblk * 128 + scol, v8);
      __syncthreads();  // all 512 per-thread drains done
      if (tid == 0) fstore_s(myflag, (unsigned)(t + 1));
    }
  }
}

// ---------------------------------------------------------------------------
// out = h_T @ Wlin^T + blin; mu = cols [0,256), logvar = cols [256,512).
// ---------------------------------------------------------------------------
__global__ __launch_bounds__(256) void final_linear(
    const float* __restrict__ hfin, const float* __restrict__ Wlin,
    const float* __restrict__ blin, float* __restrict__ out) {
  __shared__ float sh[16 * 516];
  const int tid = threadIdx.x;
  const int b0 = blockIdx.y * 16, o0 = blockIdx.x * 16;

  for (int j = tid; j < 16 * 128; j += 256) {
    int row = j >> 7, kq = j & 127;
    *(float4*)&sh[row * 516 + kq * 4] =
        *(const float4*)(hfin + (size_t)(b0 + row) * NH + kq * 4);
  }
  __syncthreads();

  const int bi = tid & 15, oi = tid >> 4;
  const int o = o0 + oi;
  const float4* wp = (const float4*)(Wlin + (size_t)o * NH);
  float4 a4 = {0.f, 0.f, 0.f, 0.f};
  for (int k4 = 0; k4 < 128; ++k4) {
    float4 wv = wp[k4];
    float4 hv = *(const float4*)&sh[bi * 516 + k4 * 4];
    a4.x += wv.x * hv.x; a4.y += wv.y * hv.y;
    a4.z += wv.z * hv.z; a4.w += wv.w * hv.w;
  }
  float v = a4.x + a4.y + a4.z + a4.w + blin[o];
  int b = b0 + bi;
  if (o < 256) out[b * 256 + o] = v;
  else out[32768 + b * 256 + (o - 256)] = v;
}

// ---------------------------------------------------------------------------
extern "C" void kernel_launch(void* const* d_in, const int* in_sizes, int n_in,
                              void* d_out, int out_size, void* d_ws, size_t ws_size,
                              hipStream_t stream) {
  const float* x    = (const float*)d_in[0];
  const float* Wih  = (const float*)d_in[1];
  const float* Whh  = (const float*)d_in[2];
  const float* bias = (const float*)d_in[3];
  const float* bn   = (const float*)d_in[4];
  const float* Wlin = (const float*)d_in[5];
  const float* blin = (const float*)d_in[6];
  float* out = (float*)d_out;

  char* ws = (char*)d_ws;
  // layout: [hbuf 262144][flags 1024][hfin 262144][IG 201326592]
  unsigned short* hbuf = (unsigned short*)ws;
  unsigned* flags      = (unsigned*)(ws + 262144);
  float* hfin          = (float*)(ws + 263168);
  unsigned short* IG   = (unsigned short*)(ws + 525312);
  const size_t need_min = 525312;
  const size_t need_ig  = need_min + (size_t)NB * NT * NG * 2;  // ~202 MB
  if (ws_size < need_min) return;

  // h slot0 = h_0 = 0; flags = 0 (graph-capture-safe)
  hipMemsetAsync(ws, 0, 131072, stream);
  hipMemsetAsync(ws + 262144, 0, 1024, stream);

  const bool useIG = (ws_size >= need_ig);
  if (useIG) {
    ig_gemm<<<dim3(12, 512), 256, 0, stream>>>(x, Wih, bias, IG);
    gru_rec<true><<<32, 512, 0, stream>>>(x, Wih, Whh, bias, bn, IG, hbuf, flags, hfin);
  } else {
    gru_rec<false><<<32, 512, 0, stream>>>(x, Wih, Whh, bias, bn, nullptr, hbuf, flags, hfin);
  }
  final_linear<<<dim3(32, 8), 256, 0, stream>>>(hfin, Wlin, blin, out);
}

// Round 5
// 2186.132 us; speedup vs baseline: 1.0808x; 1.0808x over previous
//
#include <hip/hip_runtime.h>
#include <stdint.h>

// ---------------------------------------------------------------------------
// GRU encoder (B=128,T=512,D=512,H=512,L=256), MI355X gfx950.
//
// R9 = R8 geometry (32 blocks x 512 thr, LDS-staged h slab, coalesced 8B
// stores) with the FLAG HANDOFF CHAIN REMOVED (it was ~5000cy of the 9100cy
// step): in-band sentinel at per-thread 16B granule.
//   - h ring: 4 slots of 128KB. slot0 pre-zeroed (=h_0, valid), slots1-3
//     pre-set to 0xFFFF (bf16 NaN). h in [-1,1] (convex combo of tanh and
//     prev h) so f2bf(h) can never be 0xFFFF -> sentinel unambiguous
//     (bound already correctness-proven by the R5 run, which passed).
//   - consumer (fill): each thread loads its 2x16B granules of h_t slot and
//     re-probes ONLY granules still containing 0xFFFF. No poll, no flags,
//     no producer drain on the critical path. Own 128-col slice comes from
//     ts (LDS) as in R8.
//   - producer: after the fill barrier, issue 8B sentinel store into slot
//     (t+2)&3 at this thread's OWN data-cell address (no drain). The
//     vmcnt(0) already required before the transpose barrier drains every
//     thread's sentinel; the barrier then orders ALL sentinels before ANY
//     of the block's h_{t+1} data stores (which go out with NO drain).
//   Ordering proof (per 8B cell, single producer thread X of block P):
//     consumer reads slot s as h_{t+2} only during its iter t+2, which it
//     reaches only after observing P's h_{t+1} bytes in iter t+1's fill;
//     P's h_{t+1} stores happen-after (drain+barrier) all P's sentinels of
//     slot s => sentinel visible before any new data observed => consumer
//     can only see {sentinel, h_{t+2}} in slot s, never stale h_{t-2}.
//   Readers-done (sentinel may overwrite h_{t-2}): P at iter t observed
//     peers' h_t => each peer finished iter t-1 => finished its iter t-2
//     fill reads of h_{t-2}. Ring R=4 gives the 2-step separation.
// ---------------------------------------------------------------------------

typedef short short8 __attribute__((ext_vector_type(8)));
typedef float f32x4 __attribute__((ext_vector_type(4)));
typedef int int4v __attribute__((ext_vector_type(4)));

#define NB 128
#define NT 512
#define ND 512
#define NH 512
#define NG 1536   // 3H
#define HSLOT (NB * NH)  // shorts per h ring slot (128 KB)

__device__ __forceinline__ unsigned short f2bf(float f) {
  union { float f; unsigned u; } v; v.f = f;
  unsigned r = v.u + 0x7fffu + ((v.u >> 16) & 1u);  // RNE
  return (unsigned short)(r >> 16);
}
__device__ __forceinline__ float bf2f(unsigned short u) {
  union { unsigned u; float f; } v; v.u = ((unsigned)u) << 16; return v.f;
}
__device__ __forceinline__ float sigmoid_f(float x) {
  float e = __builtin_amdgcn_exp2f(-1.4426950408889634f * x);
  return __builtin_amdgcn_rcpf(1.0f + e);
}
__device__ __forceinline__ float tanh_f(float x) {
  float e = __builtin_amdgcn_exp2f(2.8853900817779268f * x);
  return 1.0f - 2.0f * __builtin_amdgcn_rcpf(1.0f + e);
}
__device__ __forceinline__ short8 pack8(float4 a, float4 b) {
  short8 s;
  s[0] = (short)f2bf(a.x); s[1] = (short)f2bf(a.y);
  s[2] = (short)f2bf(a.z); s[3] = (short)f2bf(a.w);
  s[4] = (short)f2bf(b.x); s[5] = (short)f2bf(b.y);
  s[6] = (short)f2bf(b.z); s[7] = (short)f2bf(b.w);
  return s;
}

__device__ __forceinline__ int4v load16_s(const unsigned short* p) {
  int4v v;
  asm volatile("global_load_dwordx4 %0, %1, off sc0 sc1\n\t"
               "s_waitcnt vmcnt(0)"
               : "=v"(v) : "v"(p) : "memory");
  return v;
}

__device__ __forceinline__ void load16x2_s(const unsigned short* p0,
                                           const unsigned short* p1,
                                           int4v* v0, int4v* v1) {
  asm volatile(
      "global_load_dwordx4 %0, %2, off sc0 sc1\n\t"
      "global_load_dwordx4 %1, %3, off sc0 sc1\n\t"
      "s_waitcnt vmcnt(0)"
      : "=&v"(*v0), "=&v"(*v1) : "v"(p0), "v"(p1) : "memory");
}

// coalesced coherent 8B store, NO drain (ordering via sentinel protocol)
__device__ __forceinline__ void store8_nd(unsigned short* p, unsigned long long v) {
  asm volatile("global_store_dwordx2 %0, %1, off sc0 sc1"
               :: "v"(p), "v"(v) : "memory");
}

__device__ __forceinline__ unsigned pkmax(unsigned a, unsigned b) {
  unsigned d;
  asm("v_pk_max_u16 %0, %1, %2" : "=v"(d) : "v"(a), "v"(b));
  return d;
}
__device__ __forceinline__ bool has_sent(int4v v) {
  unsigned m = pkmax(pkmax((unsigned)v[0], (unsigned)v[1]),
                     pkmax((unsigned)v[2], (unsigned)v[3]));
  return ((m & 0xFFFFu) == 0xFFFFu) || ((m >> 16) == 0xFFFFu);
}

// ---------------------------------------------------------------------------
// IG = x @ Wih^T + bias, bf16 out. M=65536, N=1536, K=512.
// Grid dim3(12,512): bn fastest so the 12 blocks sharing one x-panel co-run.
// ---------------------------------------------------------------------------
__global__ __launch_bounds__(256) void ig_gemm(
    const float* __restrict__ x, const float* __restrict__ Wih,
    const float* __restrict__ bias, unsigned short* __restrict__ IG) {
  __shared__ unsigned short As[128 * 40];
  __shared__ unsigned short Bs[128 * 40];
  const int tid = threadIdx.x;
  const int bn = blockIdx.x, bm = blockIdx.y;
  const int lane = tid & 63, w = tid >> 6;
  const int wm = w >> 1, wn = w & 1;
  const int l15 = lane & 15, q = lane >> 4;

  f32x4 acc[4][4] = {};

  for (int kt = 0; kt < 16; ++kt) {
    __syncthreads();
#pragma unroll
    for (int j = 0; j < 4; ++j) {
      int fi = tid + 256 * j;
      int row = fi >> 3, kq = fi & 7;
      float4 v = *(const float4*)(x + (size_t)(bm * 128 + row) * ND + kt * 32 + kq * 4);
      ushort4 s = {f2bf(v.x), f2bf(v.y), f2bf(v.z), f2bf(v.w)};
      *(ushort4*)&As[row * 40 + kq * 4] = s;
    }
#pragma unroll
    for (int j = 0; j < 4; ++j) {
      int fi = tid + 256 * j;
      int row = fi >> 3, kq = fi & 7;
      float4 v = *(const float4*)(Wih + (size_t)(bn * 128 + row) * ND + kt * 32 + kq * 4);
      ushort4 s = {f2bf(v.x), f2bf(v.y), f2bf(v.z), f2bf(v.w)};
      *(ushort4*)&Bs[row * 40 + kq * 4] = s;
    }
    __syncthreads();

    short8 af[4], bf[4];
#pragma unroll
    for (int tm = 0; tm < 4; ++tm)
      af[tm] = *(const short8*)&As[(wm * 64 + tm * 16 + l15) * 40 + q * 8];
#pragma unroll
    for (int tn = 0; tn < 4; ++tn)
      bf[tn] = *(const short8*)&Bs[(wn * 64 + tn * 16 + l15) * 40 + q * 8];
#pragma unroll
    for (int tm = 0; tm < 4; ++tm)
#pragma unroll
      for (int tn = 0; tn < 4; ++tn)
        acc[tm][tn] = __builtin_amdgcn_mfma_f32_16x16x32_bf16(af[tm], bf[tn], acc[tm][tn], 0, 0, 0);
  }

#pragma unroll
  for (int tm = 0; tm < 4; ++tm) {
#pragma unroll
    for (int tn = 0; tn < 4; ++tn) {
      int col = bn * 128 + wn * 64 + tn * 16 + l15;
      float bb = bias[col];
#pragma unroll
      for (int i = 0; i < 4; ++i) {
        int row = bm * 128 + wm * 64 + tm * 16 + q * 4 + i;
        IG[(size_t)row * NG + col] = f2bf(acc[tm][tn][i] + bb);
      }
    }
  }
}

// ---------------------------------------------------------------------------
// Persistent GRU recurrence. 32 blocks x 512 threads.
// block: g = bid&7 (rows g*16..+16), cblk = bid>>3 (cols cblk*128..+128).
// wave w (0..7): 16 rows x 16 cols at col cblk*128 + w*16.
// h exchange: 4-slot sentinel ring (header comment).
// ---------------------------------------------------------------------------
template <bool USE_IG>
__global__ __launch_bounds__(512, 2) void gru_rec(
    const float* __restrict__ x, const float* __restrict__ Wih,
    const float* __restrict__ Whh, const float* __restrict__ bias,
    const float* __restrict__ bn, const unsigned short* __restrict__ IG,
    unsigned short* __restrict__ hbuf, float* __restrict__ hfin) {
  __shared__ unsigned short hs[16 * 512];  // h_t slab, swizzled (16 KB)
  __shared__ unsigned short ts[16 * 128];  // own h_{t+1} slice, row-major (4 KB)

  const int tid = threadIdx.x;
  const int lane = tid & 63;
  const int w = tid >> 6;                  // 0..7
  const int l15 = lane & 15, q = lane >> 4;
  const int bid = blockIdx.x;
  const int g = bid & 7, cblk = bid >> 3;
  const int col = cblk * 128 + w * 16 + l15;  // this lane's h column
  const int erow = g * 16 + q * 4;            // C-layout batch row base
  const int mrow = g * 16 + l15;              // A-fragment batch row (!USE_IG path)

  // Whh B-fragments -> registers: 3 gates x 16 k-chunks (192 regs)
  short8 bfr[3][16];
#pragma unroll
  for (int gt = 0; gt < 3; ++gt) {
    const float* src = Whh + (size_t)(gt * NH + col) * NH + q * 8;
#pragma unroll
    for (int kk = 0; kk < 16; ++kk) {
      float4 v0 = *(const float4*)(src + kk * 32);
      float4 v1 = *(const float4*)(src + kk * 32 + 4);
      bfr[gt][kk] = pack8(v0, v1);
    }
  }

  float bi_r = 0.f, bi_z = 0.f, bi_n = 0.f;
  if (!USE_IG) {
    bi_r = bias[col];
    bi_z = bias[NH + col];
    bi_n = bias[2 * NH + col];
  }
  const float bnv = bn[col];

  float hreg[4] = {0.f, 0.f, 0.f, 0.f};

  // fill indices (fixed per thread): 64 16B-slots per row, 2 per thread.
  const int frow = tid >> 5;          // 0..15
  const int fsi = (tid & 31) * 2;     // even slot index 0..62
  const int fr7 = frow & 7;
  const bool own_slot = ((fsi >> 4) == cblk);  // swizzle keeps 16-window

  // coalesced-store / sentinel indices: 8B per thread at (srow, scol)
  const int srow = tid >> 5;          // 0..15
  const int scol = (tid & 31) * 4;    // shorts
  const size_t cell_off = (size_t)(g * 16 + srow) * NH + cblk * 128 + scol;

  for (int t = 0; t < NT; ++t) {
    const unsigned short* hcur = hbuf + (size_t)(t & 3) * HSLOT;
    unsigned short* hnxt  = hbuf + (size_t)((t + 1) & 3) * HSLOT;
    unsigned short* hsent = hbuf + (size_t)((t + 2) & 3) * HSLOT;

    // IG loads first (plain cached loads; latency overlaps the fill).
    float igr[4], igz[4], ign[4];
    if (USE_IG) {
#pragma unroll
      for (int i = 0; i < 4; ++i) {
        const size_t base = ((size_t)(erow + i) * NT + t) * NG + col;
        igr[i] = bf2f(IG[base]);
        igz[i] = bf2f(IG[base + NH]);
        ign[i] = bf2f(IG[base + 2 * NH]);
      }
    }

    // fill: h_t[16x512] -> LDS (swizzled: LDS slot s holds global slot
    // s^(row&7)). Own slice via ts (LDS->LDS); peer slices via sentinel-
    // retry coherent loads at 16B granule.
    if (t > 0 && own_slot) {
      const int ls0 = (fsi ^ fr7) & 15;
      const int ls1 = ((fsi + 1) ^ fr7) & 15;
      *(int4v*)&hs[frow * 512 + (fsi << 3)] =
          *(const int4v*)&ts[frow * 128 + ls0 * 8];
      *(int4v*)&hs[frow * 512 + ((fsi + 1) << 3)] =
          *(const int4v*)&ts[frow * 128 + ls1 * 8];
    } else {
      const unsigned short* hrow = hcur + (size_t)(g * 16 + frow) * NH;
      const unsigned short* p0 = hrow + ((fsi ^ fr7) << 3);
      const unsigned short* p1 = hrow + (((fsi + 1) ^ fr7) << 3);
      int4v v0, v1;
      load16x2_s(p0, p1, &v0, &v1);
      if (t > 0) {  // t==0: slot0 pre-zeroed = h_0, always valid
        while (has_sent(v0)) v0 = load16_s(p0);
        while (has_sent(v1)) v1 = load16_s(p1);
      }
      *(int4v*)&hs[frow * 512 + (fsi << 3)] = v0;
      *(int4v*)&hs[frow * 512 + ((fsi + 1) << 3)] = v1;
    }
    __syncthreads();

    // sentinel slot t+2 at my own data cell (no drain here; the vmcnt(0)
    // before the transpose barrier drains it ahead of any data store).
    if (t + 2 < NT) {
      store8_nd(hsent + cell_off, 0xFFFFFFFFFFFFFFFFull);
    }

    f32x4 ar = {0.f, 0.f, 0.f, 0.f};
    f32x4 az = {0.f, 0.f, 0.f, 0.f};
    f32x4 an = {0.f, 0.f, 0.f, 0.f};
    f32x4 ai = {0.f, 0.f, 0.f, 0.f};
    const int abase = l15 * 512;
    const int ar7 = (l15 & 7) << 3;
#pragma unroll
    for (int kk = 0; kk < 16; ++kk) {
      short8 afk = *(const short8*)&hs[abase + ((kk * 32 + q * 8) ^ ar7)];
      ar = __builtin_amdgcn_mfma_f32_16x16x32_bf16(afk, bfr[0][kk], ar, 0, 0, 0);
      az = __builtin_amdgcn_mfma_f32_16x16x32_bf16(afk, bfr[1][kk], az, 0, 0, 0);
      an = __builtin_amdgcn_mfma_f32_16x16x32_bf16(afk, bfr[2][kk], an, 0, 0, 0);
      if (!USE_IG) {
        const float* xp = x + ((size_t)mrow * NT + t) * ND + kk * 32 + q * 8;
        short8 xa = pack8(*(const float4*)xp, *(const float4*)(xp + 4));
#pragma unroll
        for (int gt = 0; gt < 3; ++gt) {
          const float* wp = Wih + (size_t)(gt * NH + col) * ND + kk * 32 + q * 8;
          short8 wf = pack8(*(const float4*)wp, *(const float4*)(wp + 4));
          if (gt == 0) ar = __builtin_amdgcn_mfma_f32_16x16x32_bf16(xa, wf, ar, 0, 0, 0);
          if (gt == 1) az = __builtin_amdgcn_mfma_f32_16x16x32_bf16(xa, wf, az, 0, 0, 0);
          if (gt == 2) ai = __builtin_amdgcn_mfma_f32_16x16x32_bf16(xa, wf, ai, 0, 0, 0);
        }
      }
    }

    // gates + h update
    unsigned short sv[4];
#pragma unroll
    for (int i = 0; i < 4; ++i) {
      float xr = USE_IG ? (ar[i] + igr[i]) : (ar[i] + bi_r);
      float xz = USE_IG ? (az[i] + igz[i]) : (az[i] + bi_z);
      float xin = USE_IG ? ign[i] : (ai[i] + bi_n);
      float r = sigmoid_f(xr);
      float z = sigmoid_f(xz);
      float n = tanh_f(xin + r * (an[i] + bnv));
      float hn2 = (1.f - z) * n + z * hreg[i];
      hreg[i] = hn2;
      sv[i] = f2bf(hn2);
      if (t == NT - 1) hfin[(size_t)(erow + i) * NH + col] = hn2;
    }

    if (t != NT - 1) {
      // transpose C-layout -> row-major 16x128 tile in LDS
#pragma unroll
      for (int i = 0; i < 4; ++i)
        ts[(q * 4 + i) * 128 + w * 16 + l15] = sv[i];
      // drain my sentinel (issued ~2000cy ago: nearly free), then barrier:
      // ALL sentinels visible before ANY data store of this block.
      asm volatile("s_waitcnt vmcnt(0)" ::: "memory");
      __syncthreads();
      // coalesced coherent data store, NO drain
      unsigned long long v8 = *(const unsigned long long*)&ts[srow * 128 + scol];
      store8_nd(hnxt + cell_off, v8);
    }
  }
}

// ---------------------------------------------------------------------------
// out = h_T @ Wlin^T + blin; mu = cols [0,256), logvar = cols [256,512).
// ---------------------------------------------------------------------------
__global__ __launch_bounds__(256) void final_linear(
    const float* __restrict__ hfin, const float* __restrict__ Wlin,
    const float* __restrict__ blin, float* __restrict__ out) {
  __shared__ float sh[16 * 516];
  const int tid = threadIdx.x;
  const int b0 = blockIdx.y * 16, o0 = blockIdx.x * 16;

  for (int j = tid; j < 16 * 128; j += 256) {
    int row = j >> 7, kq = j & 127;
    *(float4*)&sh[row * 516 + kq * 4] =
        *(const float4*)(hfin + (size_t)(b0 + row) * NH + kq * 4);
  }
  __syncthreads();

  const int bi = tid & 15, oi = tid >> 4;
  const int o = o0 + oi;
  const float4* wp = (const float4*)(Wlin + (size_t)o * NH);
  float4 a4 = {0.f, 0.f, 0.f, 0.f};
  for (int k4 = 0; k4 < 128; ++k4) {
    float4 wv = wp[k4];
    float4 hv = *(const float4*)&sh[bi * 516 + k4 * 4];
    a4.x += wv.x * hv.x; a4.y += wv.y * hv.y;
    a4.z += wv.z * hv.z; a4.w += wv.w * hv.w;
  }
  float v = a4.x + a4.y + a4.z + a4.w + blin[o];
  int b = b0 + bi;
  if (o < 256) out[b * 256 + o] = v;
  else out[32768 + b * 256 + (o - 256)] = v;
}

// ---------------------------------------------------------------------------
extern "C" void kernel_launch(void* const* d_in, const int* in_sizes, int n_in,
                              void* d_out, int out_size, void* d_ws, size_t ws_size,
                              hipStream_t stream) {
  const float* x    = (const float*)d_in[0];
  const float* Wih  = (const float*)d_in[1];
  const float* Whh  = (const float*)d_in[2];
  const float* bias = (const float*)d_in[3];
  const float* bn   = (const float*)d_in[4];
  const float* Wlin = (const float*)d_in[5];
  const float* blin = (const float*)d_in[6];
  float* out = (float*)d_out;

  char* ws = (char*)d_ws;
  // layout: [h ring 4*131072][hfin 262144][IG 201326592]
  unsigned short* hbuf = (unsigned short*)ws;
  float* hfin          = (float*)(ws + 4 * 131072);
  unsigned short* IG   = (unsigned short*)(ws + 4 * 131072 + 262144);
  const size_t need_min = 4 * 131072 + 262144;                  // 786432
  const size_t need_ig  = need_min + (size_t)NB * NT * NG * 2;  // ~202 MB
  if (ws_size < need_min) return;

  // slot0 = h_0 = 0; slots 1..3 = 0xFFFF sentinel (graph-capture-safe)
  hipMemsetAsync(ws, 0, 131072, stream);
  hipMemsetAsync(ws + 131072, 0xFF, 3 * 131072, stream);

  const bool useIG = (ws_size >= need_ig);
  if (useIG) {
    ig_gemm<<<dim3(12, 512), 256, 0, stream>>>(x, Wih, bias, IG);
    gru_rec<true><<<32, 512, 0, stream>>>(x, Wih, Whh, bias, bn, IG, hbuf, hfin);
  } else {
    gru_rec<false><<<32, 512, 0, stream>>>(x, Wih, Whh, bias, bn, nullptr, hbuf, hfin);
  }
  final_linear<<<dim3(32, 8), 256, 0, stream>>>(hfin, Wlin, blin, out);
}

// Round 7
// 2078.546 us; speedup vs baseline: 1.1367x; 1.0518x over previous
//
#include <hip/hip_runtime.h>
#include <stdint.h>

// ---------------------------------------------------------------------------
// GRU encoder (B=128,T=512,D=512,H=512,L=256), MI355X gfx950.
//
// R11 = R9's sentinel-ring protocol VERBATIM, re-geometried to 256-thread
// blocks to kill register spilling:
//   R7-R10 used 512-thr blocks (8 waves): placing 2 waves/EU caps the
//   unified VGPR+AGPR budget at 256/wave (counters: VGPR_Count=128 + AGPRs).
//   bfr (Whh fragments) alone is 192 regs -> guaranteed spill/remat of ~16
//   fragments per thread per step through scratch (L2-backed; latency, not
//   FETCH). R4's 256-thr blocks (VGPR_Count=216, 1 wave/EU, 512-reg budget)
//   had no spills. This round: 64 blocks x 256 thr (4 waves), block =
//   (group g of 16 rows) x (chunk c of 64 cols), community = 8 blocks/group.
//   launch_bounds(256,1) -> allocator free up to 512 regs.
// Protocol (R9, proven): 4-slot h ring; slot0 = h_0 zeroed, others 0xFFFF
//   (bf16 NaN; h in [-1,1] so f2bf(h) never 0xFFFF). Fill = sentinel-retry
//   coherent 16B loads (peer slices) / LDS ts copy (own slice). Producer:
//   sentinel slot t+2 at own 8B cell after fill barrier; vmcnt(0)+barrier
//   before data stores (sentinels globally visible before ANY data store);
//   data stores NO drain. Ordering + readers-done proofs as in R9.
// ---------------------------------------------------------------------------

typedef short short8 __attribute__((ext_vector_type(8)));
typedef float f32x4 __attribute__((ext_vector_type(4)));
typedef int int4v __attribute__((ext_vector_type(4)));

#define NB 128
#define NT 512
#define ND 512
#define NH 512
#define NG 1536   // 3H
#define HSLOT (NB * NH)  // shorts per h ring slot (128 KB)

__device__ __forceinline__ unsigned short f2bf(float f) {
  union { float f; unsigned u; } v; v.f = f;
  unsigned r = v.u + 0x7fffu + ((v.u >> 16) & 1u);  // RNE
  return (unsigned short)(r >> 16);
}
__device__ __forceinline__ float bf2f(unsigned short u) {
  union { unsigned u; float f; } v; v.u = ((unsigned)u) << 16; return v.f;
}
__device__ __forceinline__ float sigmoid_f(float x) {
  float e = __builtin_amdgcn_exp2f(-1.4426950408889634f * x);
  return __builtin_amdgcn_rcpf(1.0f + e);
}
__device__ __forceinline__ float tanh_f(float x) {
  float e = __builtin_amdgcn_exp2f(2.8853900817779268f * x);
  return 1.0f - 2.0f * __builtin_amdgcn_rcpf(1.0f + e);
}
__device__ __forceinline__ short8 pack8(float4 a, float4 b) {
  short8 s;
  s[0] = (short)f2bf(a.x); s[1] = (short)f2bf(a.y);
  s[2] = (short)f2bf(a.z); s[3] = (short)f2bf(a.w);
  s[4] = (short)f2bf(b.x); s[5] = (short)f2bf(b.y);
  s[6] = (short)f2bf(b.z); s[7] = (short)f2bf(b.w);
  return s;
}

__device__ __forceinline__ int4v load16_s(const unsigned short* p) {
  int4v v;
  asm volatile("global_load_dwordx4 %0, %1, off sc0 sc1\n\t"
               "s_waitcnt vmcnt(0)"
               : "=v"(v) : "v"(p) : "memory");
  return v;
}

// four coherent 16B loads + ONE drain (fill path)
__device__ __forceinline__ void load16x4_s(const unsigned short* p0,
                                           const unsigned short* p1,
                                           const unsigned short* p2,
                                           const unsigned short* p3,
                                           int4v* v0, int4v* v1,
                                           int4v* v2, int4v* v3) {
  asm volatile(
      "global_load_dwordx4 %0, %4, off sc0 sc1\n\t"
      "global_load_dwordx4 %1, %5, off sc0 sc1\n\t"
      "global_load_dwordx4 %2, %6, off sc0 sc1\n\t"
      "global_load_dwordx4 %3, %7, off sc0 sc1\n\t"
      "s_waitcnt vmcnt(0)"
      : "=&v"(*v0), "=&v"(*v1), "=&v"(*v2), "=&v"(*v3)
      : "v"(p0), "v"(p1), "v"(p2), "v"(p3) : "memory");
}

// coalesced coherent 8B store, NO drain (ordering via sentinel protocol)
__device__ __forceinline__ void store8_nd(unsigned short* p, unsigned long long v) {
  asm volatile("global_store_dwordx2 %0, %1, off sc0 sc1"
               :: "v"(p), "v"(v) : "memory");
}

__device__ __forceinline__ unsigned pkmax(unsigned a, unsigned b) {
  unsigned d;
  asm("v_pk_max_u16 %0, %1, %2" : "=v"(d) : "v"(a), "v"(b));
  return d;
}
__device__ __forceinline__ bool has_sent(int4v v) {
  unsigned m = pkmax(pkmax((unsigned)v[0], (unsigned)v[1]),
                     pkmax((unsigned)v[2], (unsigned)v[3]));
  return ((m & 0xFFFFu) == 0xFFFFu) || ((m >> 16) == 0xFFFFu);
}

// ---------------------------------------------------------------------------
// IG = x @ Wih^T + bias, bf16 out. M=65536, N=1536, K=512. (unchanged)
// ---------------------------------------------------------------------------
__global__ __launch_bounds__(256) void ig_gemm(
    const float* __restrict__ x, const float* __restrict__ Wih,
    const float* __restrict__ bias, unsigned short* __restrict__ IG) {
  __shared__ unsigned short As[128 * 40];
  __shared__ unsigned short Bs[128 * 40];
  const int tid = threadIdx.x;
  const int bn = blockIdx.x, bm = blockIdx.y;
  const int lane = tid & 63, w = tid >> 6;
  const int wm = w >> 1, wn = w & 1;
  const int l15 = lane & 15, q = lane >> 4;

  f32x4 acc[4][4] = {};

  for (int kt = 0; kt < 16; ++kt) {
    __syncthreads();
#pragma unroll
    for (int j = 0; j < 4; ++j) {
      int fi = tid + 256 * j;
      int row = fi >> 3, kq = fi & 7;
      float4 v = *(const float4*)(x + (size_t)(bm * 128 + row) * ND + kt * 32 + kq * 4);
      ushort4 s = {f2bf(v.x), f2bf(v.y), f2bf(v.z), f2bf(v.w)};
      *(ushort4*)&As[row * 40 + kq * 4] = s;
    }
#pragma unroll
    for (int j = 0; j < 4; ++j) {
      int fi = tid + 256 * j;
      int row = fi >> 3, kq = fi & 7;
      float4 v = *(const float4*)(Wih + (size_t)(bn * 128 + row) * ND + kt * 32 + kq * 4);
      ushort4 s = {f2bf(v.x), f2bf(v.y), f2bf(v.z), f2bf(v.w)};
      *(ushort4*)&Bs[row * 40 + kq * 4] = s;
    }
    __syncthreads();

    short8 af[4], bf[4];
#pragma unroll
    for (int tm = 0; tm < 4; ++tm)
      af[tm] = *(const short8*)&As[(wm * 64 + tm * 16 + l15) * 40 + q * 8];
#pragma unroll
    for (int tn = 0; tn < 4; ++tn)
      bf[tn] = *(const short8*)&Bs[(wn * 64 + tn * 16 + l15) * 40 + q * 8];
#pragma unroll
    for (int tm = 0; tm < 4; ++tm)
#pragma unroll
      for (int tn = 0; tn < 4; ++tn)
        acc[tm][tn] = __builtin_amdgcn_mfma_f32_16x16x32_bf16(af[tm], bf[tn], acc[tm][tn], 0, 0, 0);
  }

#pragma unroll
  for (int tm = 0; tm < 4; ++tm) {
#pragma unroll
    for (int tn = 0; tn < 4; ++tn) {
      int col = bn * 128 + wn * 64 + tn * 16 + l15;
      float bb = bias[col];
#pragma unroll
      for (int i = 0; i < 4; ++i) {
        int row = bm * 128 + wm * 64 + tm * 16 + q * 4 + i;
        IG[(size_t)row * NG + col] = f2bf(acc[tm][tn][i] + bb);
      }
    }
  }
}

// ---------------------------------------------------------------------------
// Persistent GRU recurrence. 64 blocks x 256 threads (4 waves).
// block: g = bid&7 (rows g*16..+16), c = bid>>3 (cols c*64..+64).
// wave w (0..3): 16 rows x 16 cols at col c*64 + w*16.
// h exchange: 4-slot sentinel ring (R9 protocol verbatim).
// ---------------------------------------------------------------------------
template <bool USE_IG>
__global__ __launch_bounds__(256, 1) void gru_rec(
    const float* __restrict__ x, const float* __restrict__ Wih,
    const float* __restrict__ Whh, const float* __restrict__ bias,
    const float* __restrict__ bn, const unsigned short* __restrict__ IG,
    unsigned short* __restrict__ hbuf, float* __restrict__ hfin) {
  __shared__ unsigned short hs[16 * 512];  // h_t slab, swizzled (16 KB)
  __shared__ unsigned short ts[16 * 64];   // own h_{t+1} slice (2 KB)

  const int tid = threadIdx.x;
  const int lane = tid & 63;
  const int w = tid >> 6;                  // 0..3
  const int l15 = lane & 15, q = lane >> 4;
  const int bid = blockIdx.x;
  const int g = bid & 7, c = bid >> 3;
  const int col = c * 64 + w * 16 + l15;   // this lane's h column
  const int erow = g * 16 + q * 4;         // C-layout batch row base
  const int mrow = g * 16 + l15;           // A-fragment batch row (!USE_IG)

  // Whh B-fragments -> registers: 3 gates x 16 k-chunks (192 regs; fits in
  // the 512-reg budget of a 1-wave/EU 256-thread block -> NO spills)
  short8 bfr[3][16];
#pragma unroll
  for (int gt = 0; gt < 3; ++gt) {
    const float* src = Whh + (size_t)(gt * NH + col) * NH + q * 8;
#pragma unroll
    for (int kk = 0; kk < 16; ++kk) {
      float4 v0 = *(const float4*)(src + kk * 32);
      float4 v1 = *(const float4*)(src + kk * 32 + 4);
      bfr[gt][kk] = pack8(v0, v1);
    }
  }

  float bi_r = 0.f, bi_z = 0.f, bi_n = 0.f;
  if (!USE_IG) {
    bi_r = bias[col];
    bi_z = bias[NH + col];
    bi_n = bias[2 * NH + col];
  }
  const float bnv = bn[col];

  float hreg[4] = {0.f, 0.f, 0.f, 0.f};

  // fill indices: 64 16B-granules per row, 16 rows; 4 granules per thread.
  const int frow = tid >> 4;          // 0..15
  const int fg0 = (tid & 15) * 4;     // granule base 0..60 (aligned 4)
  const int fr7 = frow & 7;
  // fg0%8 in {0,4} and XOR with fr7<8 keeps the 8-granule window ->
  // own_slot is uniform over this thread's 4 granules.
  const bool own_slot = ((fg0 >> 3) == c);

  // store / sentinel cell: 8B per thread (single producer per cell)
  const int srow = tid >> 4;          // 0..15
  const int scol = (tid & 15) * 4;    // shorts
  const size_t cell_off = (size_t)(g * 16 + srow) * NH + c * 64 + scol;

  for (int t = 0; t < NT; ++t) {
    const unsigned short* hcur = hbuf + (size_t)(t & 3) * HSLOT;
    unsigned short* hnxt  = hbuf + (size_t)((t + 1) & 3) * HSLOT;
    unsigned short* hsent = hbuf + (size_t)((t + 2) & 3) * HSLOT;

    // IG loads first (plain cached loads; latency overlaps the fill).
    float igr[4], igz[4], ign[4];
    if (USE_IG) {
#pragma unroll
      for (int i = 0; i < 4; ++i) {
        const size_t base = ((size_t)(erow + i) * NT + t) * NG + col;
        igr[i] = bf2f(IG[base]);
        igz[i] = bf2f(IG[base + NH]);
        ign[i] = bf2f(IG[base + 2 * NH]);
      }
    }

    // fill: h_t[16x512] -> hs (LDS granule s holds global granule s^(row&7)).
    // Own 64-col slice via ts (LDS->LDS); peers via sentinel-retry loads.
    if (t > 0 && own_slot) {
#pragma unroll
      for (int j = 0; j < 4; ++j) {
        const int s = fg0 + j;
        const int ls = (s ^ fr7) & 7;
        *(int4v*)&hs[frow * 512 + (s << 3)] =
            *(const int4v*)&ts[frow * 64 + ls * 8];
      }
    } else {
      const unsigned short* hrow = hcur + (size_t)(g * 16 + frow) * NH;
      const unsigned short* p0 = hrow + (((fg0 + 0) ^ fr7) << 3);
      const unsigned short* p1 = hrow + (((fg0 + 1) ^ fr7) << 3);
      const unsigned short* p2 = hrow + (((fg0 + 2) ^ fr7) << 3);
      const unsigned short* p3 = hrow + (((fg0 + 3) ^ fr7) << 3);
      int4v v0, v1, v2, v3;
      load16x4_s(p0, p1, p2, p3, &v0, &v1, &v2, &v3);
      if (t > 0) {  // t==0: slot0 pre-zeroed = h_0, always valid
        while (has_sent(v0)) v0 = load16_s(p0);
        while (has_sent(v1)) v1 = load16_s(p1);
        while (has_sent(v2)) v2 = load16_s(p2);
        while (has_sent(v3)) v3 = load16_s(p3);
      }
      *(int4v*)&hs[frow * 512 + ((fg0 + 0) << 3)] = v0;
      *(int4v*)&hs[frow * 512 + ((fg0 + 1) << 3)] = v1;
      *(int4v*)&hs[frow * 512 + ((fg0 + 2) << 3)] = v2;
      *(int4v*)&hs[frow * 512 + ((fg0 + 3) << 3)] = v3;
    }
    __syncthreads();

    // sentinel slot t+2 at my own data cell (drained by the vmcnt(0) before
    // the pre-store barrier -> visible before any of this block's data).
    if (t + 2 < NT) {
      store8_nd(hsent + cell_off, 0xFFFFFFFFFFFFFFFFull);
    }

    f32x4 ar = {0.f, 0.f, 0.f, 0.f};
    f32x4 az = {0.f, 0.f, 0.f, 0.f};
    f32x4 an = {0.f, 0.f, 0.f, 0.f};
    f32x4 ai = {0.f, 0.f, 0.f, 0.f};
    const int abase = l15 * 512;
    const int ar7 = (l15 & 7) << 3;
#pragma unroll
    for (int kk = 0; kk < 16; ++kk) {
      short8 afk = *(const short8*)&hs[abase + ((kk * 32 + q * 8) ^ ar7)];
      ar = __builtin_amdgcn_mfma_f32_16x16x32_bf16(afk, bfr[0][kk], ar, 0, 0, 0);
      az = __builtin_amdgcn_mfma_f32_16x16x32_bf16(afk, bfr[1][kk], az, 0, 0, 0);
      an = __builtin_amdgcn_mfma_f32_16x16x32_bf16(afk, bfr[2][kk], an, 0, 0, 0);
      if (!USE_IG) {
        const float* xp = x + ((size_t)mrow * NT + t) * ND + kk * 32 + q * 8;
        short8 xa = pack8(*(const float4*)xp, *(const float4*)(xp + 4));
#pragma unroll
        for (int gt = 0; gt < 3; ++gt) {
          const float* wp = Wih + (size_t)(gt * NH + col) * ND + kk * 32 + q * 8;
          short8 wf = pack8(*(const float4*)wp, *(const float4*)(wp + 4));
          if (gt == 0) ar = __builtin_amdgcn_mfma_f32_16x16x32_bf16(xa, wf, ar, 0, 0, 0);
          if (gt == 1) az = __builtin_amdgcn_mfma_f32_16x16x32_bf16(xa, wf, az, 0, 0, 0);
          if (gt == 2) ai = __builtin_amdgcn_mfma_f32_16x16x32_bf16(xa, wf, ai, 0, 0, 0);
        }
      }
    }

    // gates + h update
    unsigned short sv[4];
#pragma unroll
    for (int i = 0; i < 4; ++i) {
      float xr = USE_IG ? (ar[i] + igr[i]) : (ar[i] + bi_r);
      float xz = USE_IG ? (az[i] + igz[i]) : (az[i] + bi_z);
      float xin = USE_IG ? ign[i] : (ai[i] + bi_n);
      float r = sigmoid_f(xr);
      float z = sigmoid_f(xz);
      float n = tanh_f(xin + r * (an[i] + bnv));
      float hn2 = (1.f - z) * n + z * hreg[i];
      hreg[i] = hn2;
      sv[i] = f2bf(hn2);
      if (t == NT - 1) hfin[(size_t)(erow + i) * NH + col] = hn2;
    }

    if (t != NT - 1) {
      // transpose C-layout -> row-major 16x64 tile in ts
#pragma unroll
      for (int i = 0; i < 4; ++i)
        ts[(q * 4 + i) * 64 + w * 16 + l15] = sv[i];
      // drain my sentinel (issued ~2000cy ago: nearly free), then barrier:
      // ALL sentinels visible before ANY data store of this block.
      asm volatile("s_waitcnt vmcnt(0)" ::: "memory");
      __syncthreads();
      // coalesced coherent data store, NO drain
      unsigned long long v8 = *(const unsigned long long*)&ts[srow * 64 + scol];
      store8_nd(hnxt + cell_off, v8);
    }
  }
}

// ---------------------------------------------------------------------------
// out = h_T @ Wlin^T + blin; mu = cols [0,256), logvar = cols [256,512).
// ---------------------------------------------------------------------------
__global__ __launch_bounds__(256) void final_linear(
    const float* __restrict__ hfin, const float* __restrict__ Wlin,
    const float* __restrict__ blin, float* __restrict__ out) {
  __shared__ float sh[16 * 516];
  const int tid = threadIdx.x;
  const int b0 = blockIdx.y * 16, o0 = blockIdx.x * 16;

  for (int j = tid; j < 16 * 128; j += 256) {
    int row = j >> 7, kq = j & 127;
    *(float4*)&sh[row * 516 + kq * 4] =
        *(const float4*)(hfin + (size_t)(b0 + row) * NH + kq * 4);
  }
  __syncthreads();

  const int bi = tid & 15, oi = tid >> 4;
  const int o = o0 + oi;
  const float4* wp = (const float4*)(Wlin + (size_t)o * NH);
  float4 a4 = {0.f, 0.f, 0.f, 0.f};
  for (int k4 = 0; k4 < 128; ++k4) {
    float4 wv = wp[k4];
    float4 hv = *(const float4*)&sh[bi * 516 + k4 * 4];
    a4.x += wv.x * hv.x; a4.y += wv.y * hv.y;
    a4.z += wv.z * hv.z; a4.w += wv.w * hv.w;
  }
  float v = a4.x + a4.y + a4.z + a4.w + blin[o];
  int b = b0 + bi;
  if (o < 256) out[b * 256 + o] = v;
  else out[32768 + b * 256 + (o - 256)] = v;
}

// ---------------------------------------------------------------------------
extern "C" void kernel_launch(void* const* d_in, const int* in_sizes, int n_in,
                              void* d_out, int out_size, void* d_ws, size_t ws_size,
                              hipStream_t stream) {
  const float* x    = (const float*)d_in[0];
  const float* Wih  = (const float*)d_in[1];
  const float* Whh  = (const float*)d_in[2];
  const float* bias = (const float*)d_in[3];
  const float* bn   = (const float*)d_in[4];
  const float* Wlin = (const float*)d_in[5];
  const float* blin = (const float*)d_in[6];
  float* out = (float*)d_out;

  char* ws = (char*)d_ws;
  // layout: [h ring 4*131072][hfin 262144][IG 201326592]
  unsigned short* hbuf = (unsigned short*)ws;
  float* hfin          = (float*)(ws + 4 * 131072);
  unsigned short* IG   = (unsigned short*)(ws + 4 * 131072 + 262144);
  const size_t need_min = 4 * 131072 + 262144;                  // 786432
  const size_t need_ig  = need_min + (size_t)NB * NT * NG * 2;  // ~202 MB
  if (ws_size < need_min) return;

  // slot0 = h_0 = 0; slots 1..3 = 0xFFFF sentinel (graph-capture-safe)
  hipMemsetAsync(ws, 0, 131072, stream);
  hipMemsetAsync(ws + 131072, 0xFF, 3 * 131072, stream);

  const bool useIG = (ws_size >= need_ig);
  if (useIG) {
    ig_gemm<<<dim3(12, 512), 256, 0, stream>>>(x, Wih, bias, IG);
    gru_rec<true><<<64, 256, 0, stream>>>(x, Wih, Whh, bias, bn, IG, hbuf, hfin);
  } else {
    gru_rec<false><<<64, 256, 0, stream>>>(x, Wih, Whh, bias, bn, nullptr, hbuf, hfin);
  }
  final_linear<<<dim3(32, 8), 256, 0, stream>>>(hfin, Wlin, blin, out);
}